// Round 12
// baseline (4723.053 us; speedup 1.0000x reference)
//
#include <hip/hip_runtime.h>
#include <math.h>

#define TSTEPS 512
#define BATCH  64
#define HDIM   1024
#define IDIM   128
#define NBLOCKS 256   // 128 per layer: (jt 0..63) x (mh 0..1)
#define NTHR   512    // 8 waves: (m2 0..1) x (kh 0..3)

typedef __attribute__((ext_vector_type(8))) short bf16x8;
typedef __attribute__((ext_vector_type(4))) float f32x4;
typedef __attribute__((ext_vector_type(4))) unsigned u32x4;

// ---- ws: bf16 hi/lo weight planes (ushort units), then barrier area ----
#define WI0HI 0
#define WI0LO (WI0HI + 1024*128)
#define WH0HI (WI0LO + 1024*128)
#define WH0LO (WH0HI + 1024*1024)
#define WI1HI (WH0LO + 1024*1024)
#define WI1LO (WI1HI + 1024*1024)
#define WH1HI (WI1LO + 1024*1024)
#define WH1LO (WH1HI + 1024*1024)
#define WS_USHORTS (WH1LO + 1024*1024)
#define CNT_OFF_BYTES ((size_t)WS_USHORTS * 2)
// barrier area (dword offsets from cnt): arrivals 256 x 16, flags 256 x 16
#define FLG_DW (256 * 16)
#define BAR_BYTES (2 * 256 * 64)   // 32 KB

__device__ __forceinline__ unsigned short bf_hi(float f) {
    unsigned u = __builtin_bit_cast(unsigned, f);
    unsigned r = u + 0x7fffu + ((u >> 16) & 1u);
    return (unsigned short)(r >> 16);
}
__device__ __forceinline__ float bf_tof(unsigned short h) {
    unsigned u = ((unsigned)h) << 16;
    return __builtin_bit_cast(float, u);
}

// fp32x8 (two f32x4 VALUES) -> bf16 hi + lo fragments via v_cvt_pk_bf16_f32
__device__ __forceinline__ void split8v(f32x4 a, f32x4 b,
                                        bf16x8& ah, bf16x8& al) {
    float fv[8] = {a[0], a[1], a[2], a[3], b[0], b[1], b[2], b[3]};
    u32x4 H, L;
    #pragma unroll
    for (int q = 0; q < 4; ++q) {
        const float f0 = fv[2 * q], f1 = fv[2 * q + 1];
        unsigned h;
        asm("v_cvt_pk_bf16_f32 %0, %1, %2" : "=v"(h) : "v"(f0), "v"(f1));
        const float h0 = __builtin_bit_cast(float, h << 16);
        const float h1 = __builtin_bit_cast(float, h & 0xffff0000u);
        unsigned lo;
        asm("v_cvt_pk_bf16_f32 %0, %1, %2" : "=v"(lo) : "v"(f0 - h0), "v"(f1 - h1));
        H[q] = h; L[q] = lo;
    }
    ah = __builtin_bit_cast(bf16x8, H);
    al = __builtin_bit_cast(bf16x8, L);
}

// one 32-k chunk from PRELOADED values: split + 3 MFMA (round-8..11 numerics)
__device__ __forceinline__ void ks_r2(f32x4 a, f32x4 b,
                                      bf16x8 bh, bf16x8 bl, f32x4& acc) {
    bf16x8 ah, al;
    split8v(a, b, ah, al);
    acc = __builtin_amdgcn_mfma_f32_16x16x32_bf16(ah, bh, acc, 0, 0, 0);
    acc = __builtin_amdgcn_mfma_f32_16x16x32_bf16(al, bh, acc, 0, 0, 0);
    acc = __builtin_amdgcn_mfma_f32_16x16x32_bf16(ah, bl, acc, 0, 0, 0);
}

// load 4 chunks (8 x dwordx4) of group g into a named buffer (static idx)
#define LDG4(B, base, g) _Pragma("unroll") for (int c = 0; c < 4; ++c) { \
    (B)[2*c]   = *(const f32x4*)((base) + ((g)*4 + c) * 32); \
    (B)[2*c+1] = *(const f32x4*)((base) + ((g)*4 + c) * 32 + 4); }
// process 4 chunks of group g against weight frags wfh/wfl[wOff + g*4 + c]
#define PROC4(B, wOff, g) _Pragma("unroll") for (int c = 0; c < 4; ++c) { \
    ks_r2((B)[2*c], (B)[2*c+1], wfh[(wOff)+(g)*4+c], wfl[(wOff)+(g)*4+c], \
          ((((g)*4+c) & 1) ? accA : accB)); }

// split fp32 weights into bf16 hi/lo planes in ws ([j][k] row-major)
__global__ void prep_kernel(const float* __restrict__ Wi0, const float* __restrict__ Wh0,
                            const float* __restrict__ Wi1, const float* __restrict__ Wh1,
                            unsigned short* __restrict__ wsU)
{
    const int n = 1024*128 + 3*1024*1024;
    for (int e = blockIdx.x * blockDim.x + threadIdx.x; e < n;
         e += gridDim.x * blockDim.x) {
        const float* src; int idx, hiOff, loOff;
        if (e < 1024*128)            { src = Wi0; idx = e;              hiOff = WI0HI; loOff = WI0LO; }
        else if (e < 1024*128 + 1024*1024)   { src = Wh0; idx = e - 1024*128;   hiOff = WH0HI; loOff = WH0LO; }
        else if (e < 1024*128 + 2*1024*1024) { src = Wi1; idx = e - 1024*128 - 1024*1024; hiOff = WI1HI; loOff = WI1LO; }
        else                         { src = Wh1; idx = e - 1024*128 - 2*1024*1024; hiOff = WH1HI; loOff = WH1LO; }
        float f = src[idx];
        unsigned short h = bf_hi(f);
        wsU[hiOff + idx] = h;
        wsU[loOff + idx] = bf_hi(f - bf_tof(h));
    }
}

// --- One-reader-per-line grid barrier (round-11 proven; unchanged) ---
__device__ __forceinline__ void barrier_arrive(unsigned* cnt, unsigned epoch) {
    __syncthreads();   // drain all waves' sc1 data stores (vmcnt 0)
    if (threadIdx.x == 0)
        __hip_atomic_store(cnt + (unsigned)blockIdx.x * 16, epoch,
                           __ATOMIC_RELAXED, __HIP_MEMORY_SCOPE_AGENT);
}
__device__ __forceinline__ void barrier_wait(unsigned* cnt, unsigned epoch) {
    const int tid = (int)threadIdx.x;
    if (blockIdx.x == 0) {
        if (tid < 64) {
            unsigned* flg = cnt + FLG_DW;
            for (;;) {
                unsigned v0 = __hip_atomic_load(cnt + (tid      ) * 16, __ATOMIC_RELAXED, __HIP_MEMORY_SCOPE_AGENT);
                unsigned v1 = __hip_atomic_load(cnt + (tid +  64) * 16, __ATOMIC_RELAXED, __HIP_MEMORY_SCOPE_AGENT);
                unsigned v2 = __hip_atomic_load(cnt + (tid + 128) * 16, __ATOMIC_RELAXED, __HIP_MEMORY_SCOPE_AGENT);
                unsigned v3 = __hip_atomic_load(cnt + (tid + 192) * 16, __ATOMIC_RELAXED, __HIP_MEMORY_SCOPE_AGENT);
                bool ok = (v0 >= epoch) & (v1 >= epoch) & (v2 >= epoch) & (v3 >= epoch);
                if (__ballot(ok) == ~0ull) break;
                __builtin_amdgcn_s_sleep(1);
            }
            #pragma unroll
            for (int q = 0; q < 4; ++q)
                __hip_atomic_store(flg + (q * 64 + tid) * 16, epoch,
                                   __ATOMIC_RELAXED, __HIP_MEMORY_SCOPE_AGENT);
        }
    } else if (tid == 0) {
        unsigned* myflag = cnt + FLG_DW + (unsigned)blockIdx.x * 16;
        while (__hip_atomic_load(myflag, __ATOMIC_RELAXED,
                                 __HIP_MEMORY_SCOPE_AGENT) < epoch)
            __builtin_amdgcn_s_sleep(1);
    }
    __syncthreads();
}

// Persistent pipeline-skewed kernel. out[] IS the state trajectory; sc1
// write-through stores, normal-cached first-touch reads (round-8 proven).
// Weights in registers; A-loads double-buffered in 4-chunk groups for MLP.
__global__ __launch_bounds__(NTHR, 2) void reservoir_kernel(
    const float* __restrict__ x, float* __restrict__ out,
    const unsigned short* __restrict__ wsU, unsigned* __restrict__ cnt)
{
    __shared__ f32x4 red[8 * 64];   // 8 KB

    const int bid = blockIdx.x;
    const int layer = bid >> 7;
    const int rr  = bid & 127;
    const int jt  = rr >> 1, mh = rr & 1;
    const int tid = (int)threadIdx.x;
    const int w   = __builtin_amdgcn_readfirstlane(tid >> 6);
    const int m2  = w & 1, kh = w >> 1;
    const int l   = tid & 63, lr = l & 15, tq = l >> 4;
    const int jbase = jt * 16;
    const int arow  = mh * 32 + m2 * 16 + lr;   // this lane's A row (batch)

    // ---- load this wave's weight fragments into registers (once) ----
    bf16x8 wfh[16], wfl[16];
    if (layer == 0) {
        const size_t rx = (size_t)(jbase + lr) * IDIM + kh * 32 + tq * 8;
        wfh[0] = *(const bf16x8*)(wsU + WI0HI + rx);
        wfl[0] = *(const bf16x8*)(wsU + WI0LO + rx);
        const size_t rh = (size_t)(jbase + lr) * HDIM + kh * 256 + tq * 8;
        #pragma unroll
        for (int ks = 0; ks < 8; ++ks) {
            wfh[1 + ks] = *(const bf16x8*)(wsU + WH0HI + rh + ks * 32);
            wfl[1 + ks] = *(const bf16x8*)(wsU + WH0LO + rh + ks * 32);
        }
    } else {
        const int hiOff = (kh < 2) ? WI1HI : WH1HI;
        const int loOff = (kh < 2) ? WI1LO : WH1LO;
        const size_t ro = (size_t)(jbase + lr) * HDIM + (kh & 1) * 512 + tq * 8;
        #pragma unroll
        for (int ks = 0; ks < 16; ++ks) {
            wfh[ks] = *(const bf16x8*)(wsU + hiOff + ro + ks * 32);
            wfl[ks] = *(const bf16x8*)(wsU + loOff + ro + ks * 32);
        }
    }

    float hold[4] = {0.f, 0.f, 0.f, 0.f};
    f32x4 accX = {0.f, 0.f, 0.f, 0.f};   // layer-0 x-part prefetch

    for (int i = 0; i <= TSTEPS; ++i) {
        const int t = layer ? (i - 1) : i;
        const bool valid = layer ? (t >= 0) : (t < TSTEPS);
        if (valid) {
            f32x4 accA = {0.f, 0.f, 0.f, 0.f};
            f32x4 accB = {0.f, 0.f, 0.f, 0.f};
            if (layer == 0) {
                if (i == 0) {
                    f32x4 xa = *(const f32x4*)(x + (size_t)t * (BATCH * IDIM) + arow * IDIM + kh * 32 + tq * 8);
                    f32x4 xb = *(const f32x4*)(x + (size_t)t * (BATCH * IDIM) + arow * IDIM + kh * 32 + tq * 8 + 4);
                    ks_r2(xa, xb, wfh[0], wfl[0], accA);
                } else {
                    accA = accX;   // prefetched under the previous barrier
                }
                if (t >= 1) {   // h0[t-1] = e0[t-1] = out[t-1][.][0][.]
                    const float* h0 = out + (size_t)(t - 1) * 131072 + arow * 2048
                                      + kh * 256 + tq * 8;
                    f32x4 bA[8], bB[8];        // 2 groups, all 16 loads up front
                    LDG4(bA, h0, 0);
                    LDG4(bB, h0, 1);
                    PROC4(bA, 1, 0);
                    PROC4(bB, 1, 1);
                }
            } else {
                // kh<2: e0[t] x Wi1 slice; kh>=2: h1[t-1] x Wh1 slice
                const bool doit = (kh < 2) || (t >= 1);
                if (doit) {
                    const int ts  = (kh < 2) ? t : (t - 1);
                    const float* src = out + (size_t)ts * 131072 + arow * 2048
                                       + ((kh < 2) ? 0 : 1024) + (kh & 1) * 512 + tq * 8;
                    f32x4 bA[8], bB[8];        // 4 groups, depth-2 pipeline
                    LDG4(bA, src, 0);
                    LDG4(bB, src, 1);
                    PROC4(bA, 0, 0);
                    LDG4(bA, src, 2);
                    PROC4(bB, 0, 1);
                    LDG4(bB, src, 3);
                    PROC4(bA, 0, 2);
                    PROC4(bB, 0, 3);
                }
            }

            // cross-wave K-reduction (4 kh partials per m2)
            red[w * 64 + l] = accA + accB;
            __syncthreads();
            if (w < 2) {   // waves (m2=w, kh=0) finalize
                f32x4 s  = red[(w + 0) * 64 + l];
                f32x4 s1 = red[(w + 2) * 64 + l];
                f32x4 s2 = red[(w + 4) * 64 + l];
                f32x4 s3 = red[(w + 6) * 64 + l];
                #pragma unroll
                for (int r = 0; r < 4; ++r) {
                    const float pre = ((s[r] + s1[r]) + (s2[r] + s3[r]));
                    const float hnew = 0.5f * hold[r] + 0.5f * tanhf(pre);
                    hold[r] = hnew;
                    const int row = mh * 32 + w * 16 + tq * 4 + r;   // C/D: row=(l>>4)*4+r
                    const int col = jbase + lr;                       // col=l&15
                    float* dst = out + (size_t)t * 131072 + row * 2048 + layer * 1024 + col;
                    __hip_atomic_store(dst, hnew, __ATOMIC_RELAXED, __HIP_MEMORY_SCOPE_AGENT);
                }
            }
            __syncthreads();   // red reuse safety
        }
        if (i < TSTEPS) {
            barrier_arrive(cnt, (unsigned)(i + 1));
            // overlap: layer-0's x-part for step i+1 is barrier-independent
            if (layer == 0 && (i + 1) < TSTEPS) {
                const float* xs = x + (size_t)(i + 1) * (BATCH * IDIM) + arow * IDIM + kh * 32 + tq * 8;
                f32x4 xa = *(const f32x4*)(xs);
                f32x4 xb = *(const f32x4*)(xs + 4);
                f32x4 z = {0.f, 0.f, 0.f, 0.f};
                ks_r2(xa, xb, wfh[0], wfl[0], z);
                accX = z;
            }
            barrier_wait(cnt, (unsigned)(i + 1));
        }
    }
}

extern "C" void kernel_launch(void* const* d_in, const int* in_sizes, int n_in,
                              void* d_out, int out_size, void* d_ws, size_t ws_size,
                              hipStream_t stream) {
    const float* x   = (const float*)d_in[0];
    const float* Wi0 = (const float*)d_in[1];
    const float* Wh0 = (const float*)d_in[2];
    const float* Wi1 = (const float*)d_in[3];
    const float* Wh1 = (const float*)d_in[4];
    float* out = (float*)d_out;
    unsigned short* wsU = (unsigned short*)d_ws;
    unsigned* cnt = (unsigned*)((char*)d_ws + CNT_OFF_BYTES);

    // arrival + flag lines must be 0 at kernel start on EVERY replay
    hipMemsetAsync((char*)d_ws + CNT_OFF_BYTES, 0, BAR_BYTES, stream);
    prep_kernel<<<256, 256, 0, stream>>>(Wi0, Wh0, Wi1, Wh1, wsU);

    void* args[] = {(void*)&x, (void*)&out, (void*)&wsU, (void*)&cnt};
    hipLaunchCooperativeKernel((const void*)reservoir_kernel,
                               dim3(NBLOCKS), dim3(NTHR), args, 0, stream);
}

// Round 13
// 4619.559 us; speedup vs baseline: 1.0224x; 1.0224x over previous
//
#include <hip/hip_runtime.h>
#include <math.h>

#define TSTEPS 512
#define BATCH  64
#define HDIM   1024
#define IDIM   128
#define NBLOCKS 256   // blocks 0..127: layer 0; 128..255: layer 1
#define NTHR   512    // 8 waves: (m2 0..1) x (kh 0..3)

typedef __attribute__((ext_vector_type(8))) short bf16x8;
typedef __attribute__((ext_vector_type(4))) float f32x4;
typedef __attribute__((ext_vector_type(4))) unsigned u32x4;

// ---- ws: bf16 hi/lo weight planes (ushort units), then barrier area ----
#define WI0HI 0
#define WI0LO (WI0HI + 1024*128)
#define WH0HI (WI0LO + 1024*128)
#define WH0LO (WH0HI + 1024*1024)
#define WI1HI (WH0LO + 1024*1024)
#define WI1LO (WI1HI + 1024*1024)
#define WH1HI (WI1LO + 1024*1024)
#define WH1LO (WH1HI + 1024*1024)
#define WS_USHORTS (WH1LO + 1024*1024)
#define CNT_OFF_BYTES ((size_t)WS_USHORTS * 2)
// barrier area (dword offsets from cnt):
//   arrivals: 256 lines (L0 = 0..127, L1 = 128..255)
//   flagL0:   256 lines at FLG_DW      (published by block 0)
//   flagL1:   256 lines at FLG_DW+4096 (published by block 128)
#define FLG_DW (256 * 16)
#define BAR_BYTES (3 * 256 * 64)   // 48 KB

__device__ __forceinline__ unsigned short bf_hi(float f) {
    unsigned u = __builtin_bit_cast(unsigned, f);
    unsigned r = u + 0x7fffu + ((u >> 16) & 1u);
    return (unsigned short)(r >> 16);
}
__device__ __forceinline__ float bf_tof(unsigned short h) {
    unsigned u = ((unsigned)h) << 16;
    return __builtin_bit_cast(float, u);
}

// fp32x8 (two f32x4 VALUES) -> bf16 hi + lo fragments via v_cvt_pk_bf16_f32
__device__ __forceinline__ void split8v(f32x4 a, f32x4 b,
                                        bf16x8& ah, bf16x8& al) {
    float fv[8] = {a[0], a[1], a[2], a[3], b[0], b[1], b[2], b[3]};
    u32x4 H, L;
    #pragma unroll
    for (int q = 0; q < 4; ++q) {
        const float f0 = fv[2 * q], f1 = fv[2 * q + 1];
        unsigned h;
        asm("v_cvt_pk_bf16_f32 %0, %1, %2" : "=v"(h) : "v"(f0), "v"(f1));
        const float h0 = __builtin_bit_cast(float, h << 16);
        const float h1 = __builtin_bit_cast(float, h & 0xffff0000u);
        unsigned lo;
        asm("v_cvt_pk_bf16_f32 %0, %1, %2" : "=v"(lo) : "v"(f0 - h0), "v"(f1 - h1));
        H[q] = h; L[q] = lo;
    }
    ah = __builtin_bit_cast(bf16x8, H);
    al = __builtin_bit_cast(bf16x8, L);
}

// one 32-k chunk from PRELOADED values: split + 3 MFMA (round-8..12 numerics)
__device__ __forceinline__ void ks_r2(f32x4 a, f32x4 b,
                                      bf16x8 bh, bf16x8 bl, f32x4& acc) {
    bf16x8 ah, al;
    split8v(a, b, ah, al);
    acc = __builtin_amdgcn_mfma_f32_16x16x32_bf16(ah, bh, acc, 0, 0, 0);
    acc = __builtin_amdgcn_mfma_f32_16x16x32_bf16(al, bh, acc, 0, 0, 0);
    acc = __builtin_amdgcn_mfma_f32_16x16x32_bf16(ah, bl, acc, 0, 0, 0);
}

// load 4 chunks (8 x dwordx4) of group g into a named buffer (static idx)
#define LDG4(B, base, g) _Pragma("unroll") for (int c = 0; c < 4; ++c) { \
    (B)[2*c]   = *(const f32x4*)((base) + ((g)*4 + c) * 32); \
    (B)[2*c+1] = *(const f32x4*)((base) + ((g)*4 + c) * 32 + 4); }
// process 4 chunks of group g against weight frags wfh/wfl[wOff + g*4 + c]
#define PROC4(B, wOff, g) _Pragma("unroll") for (int c = 0; c < 4; ++c) { \
    ks_r2((B)[2*c], (B)[2*c+1], wfh[(wOff)+(g)*4+c], wfl[(wOff)+(g)*4+c], \
          ((((g)*4+c) & 1) ? accA : accB)); }

// split fp32 weights into bf16 hi/lo planes in ws ([j][k] row-major)
__global__ void prep_kernel(const float* __restrict__ Wi0, const float* __restrict__ Wh0,
                            const float* __restrict__ Wi1, const float* __restrict__ Wh1,
                            unsigned short* __restrict__ wsU)
{
    const int n = 1024*128 + 3*1024*1024;
    for (int e = blockIdx.x * blockDim.x + threadIdx.x; e < n;
         e += gridDim.x * blockDim.x) {
        const float* src; int idx, hiOff, loOff;
        if (e < 1024*128)            { src = Wi0; idx = e;              hiOff = WI0HI; loOff = WI0LO; }
        else if (e < 1024*128 + 1024*1024)   { src = Wh0; idx = e - 1024*128;   hiOff = WH0HI; loOff = WH0LO; }
        else if (e < 1024*128 + 2*1024*1024) { src = Wi1; idx = e - 1024*128 - 1024*1024; hiOff = WI1HI; loOff = WI1LO; }
        else                         { src = Wh1; idx = e - 1024*128 - 2*1024*1024; hiOff = WH1HI; loOff = WH1LO; }
        float f = src[idx];
        unsigned short h = bf_hi(f);
        wsU[hiOff + idx] = h;
        wsU[loOff + idx] = bf_hi(f - bf_tof(h));
    }
}

// --- Layer-decoupled one-reader-per-line barriers ---
// Each layer is an independent 128-block domain with its own aggregator
// (block 0 / block 128) and its own flag array. L0 blocks wait only on
// flagL0 (own-layer e0 ready) -> L0 free-runs ahead of L1. L1 blocks wait
// on flagL1 (own h1 ready) AND flagL0 (e0[t] ready; satisfied early since
// L0 leads). Ordering chain identical to rounds 8-12: sc1 data stores
// drained by the arrive-side __syncthreads; epochs monotonic; flags
// published only after all domain arrivals observed.
__device__ __forceinline__ void barrier_arrive(unsigned* cnt, unsigned epoch) {
    __syncthreads();   // drain all waves' sc1 data stores (vmcnt 0)
    if (threadIdx.x == 0)
        __hip_atomic_store(cnt + (unsigned)blockIdx.x * 16, epoch,
                           __ATOMIC_RELAXED, __HIP_MEMORY_SCOPE_AGENT);
}
__device__ __forceinline__ void barrier_wait(unsigned* cnt, unsigned epoch, int layer) {
    const int tid = (int)threadIdx.x;
    const int bid = (int)blockIdx.x;
    if ((bid & 127) == 0) {
        // this layer's aggregator: sweep 128 arrival lines, publish flags
        if (tid < 64) {
            unsigned* arr = cnt + layer * (128 * 16);
            for (;;) {
                unsigned v0 = __hip_atomic_load(arr + (tid     ) * 16, __ATOMIC_RELAXED, __HIP_MEMORY_SCOPE_AGENT);
                unsigned v1 = __hip_atomic_load(arr + (tid + 64) * 16, __ATOMIC_RELAXED, __HIP_MEMORY_SCOPE_AGENT);
                bool ok = (v0 >= epoch) & (v1 >= epoch);
                if (__ballot(ok) == ~0ull) break;
                __builtin_amdgcn_s_sleep(1);
            }
            unsigned* flg = cnt + FLG_DW + layer * 4096;
            #pragma unroll
            for (int q = 0; q < 4; ++q)
                __hip_atomic_store(flg + (q * 64 + tid) * 16, epoch,
                                   __ATOMIC_RELAXED, __HIP_MEMORY_SCOPE_AGENT);
        }
        // L1 aggregator must also observe L0's epoch (e0[t] ready)
        if (layer == 1 && tid == 0) {
            unsigned* f0 = cnt + FLG_DW + (unsigned)bid * 16;
            while (__hip_atomic_load(f0, __ATOMIC_RELAXED,
                                     __HIP_MEMORY_SCOPE_AGENT) < epoch)
                __builtin_amdgcn_s_sleep(1);
        }
    } else if (tid == 0) {
        unsigned* f0 = cnt + FLG_DW + (unsigned)bid * 16;
        if (layer == 0) {
            while (__hip_atomic_load(f0, __ATOMIC_RELAXED,
                                     __HIP_MEMORY_SCOPE_AGENT) < epoch)
                __builtin_amdgcn_s_sleep(1);
        } else {
            unsigned* f1 = cnt + FLG_DW + 4096 + (unsigned)bid * 16;
            for (;;) {
                unsigned a = __hip_atomic_load(f1, __ATOMIC_RELAXED, __HIP_MEMORY_SCOPE_AGENT);
                unsigned b = __hip_atomic_load(f0, __ATOMIC_RELAXED, __HIP_MEMORY_SCOPE_AGENT);
                if (a >= epoch && b >= epoch) break;
                __builtin_amdgcn_s_sleep(1);
            }
        }
    }
    __syncthreads();
}

// Persistent layer-decoupled kernel. out[] IS the state trajectory; sc1
// write-through stores, normal-cached first-touch reads (round-8 proven).
// Weights in registers; A-loads grouped for MLP; all-thread finalize.
__global__ __launch_bounds__(NTHR, 2) void reservoir_kernel(
    const float* __restrict__ x, float* __restrict__ out,
    const unsigned short* __restrict__ wsU, unsigned* __restrict__ cnt)
{
    __shared__ f32x4 red[8 * 64];   // 8 KB

    const int bid = blockIdx.x;
    const int layer = bid >> 7;
    const int rr  = bid & 127;
    const int jt  = rr >> 1, mh = rr & 1;
    const int tid = (int)threadIdx.x;
    const int w   = __builtin_amdgcn_readfirstlane(tid >> 6);
    const int m2  = w & 1, kh = w >> 1;
    const int l   = tid & 63, lr = l & 15, tq = l >> 4;
    const int jbase = jt * 16;
    const int arow  = mh * 32 + m2 * 16 + lr;   // this lane's A row (batch)

    // ---- load this wave's weight fragments into registers (once) ----
    bf16x8 wfh[16], wfl[16];
    if (layer == 0) {
        const size_t rx = (size_t)(jbase + lr) * IDIM + kh * 32 + tq * 8;
        wfh[0] = *(const bf16x8*)(wsU + WI0HI + rx);
        wfl[0] = *(const bf16x8*)(wsU + WI0LO + rx);
        const size_t rh = (size_t)(jbase + lr) * HDIM + kh * 256 + tq * 8;
        #pragma unroll
        for (int ks = 0; ks < 8; ++ks) {
            wfh[1 + ks] = *(const bf16x8*)(wsU + WH0HI + rh + ks * 32);
            wfl[1 + ks] = *(const bf16x8*)(wsU + WH0LO + rh + ks * 32);
        }
    } else {
        const int hiOff = (kh < 2) ? WI1HI : WH1HI;
        const int loOff = (kh < 2) ? WI1LO : WH1LO;
        const size_t ro = (size_t)(jbase + lr) * HDIM + (kh & 1) * 512 + tq * 8;
        #pragma unroll
        for (int ks = 0; ks < 16; ++ks) {
            wfh[ks] = *(const bf16x8*)(wsU + hiOff + ro + ks * 32);
            wfl[ks] = *(const bf16x8*)(wsU + loOff + ro + ks * 32);
        }
    }

    // all-thread finalize: this thread owns output (rowF, colF) of the tile
    const int rowLocal = tid >> 4;            // 0..31
    const int colF = tid & 15;
    const int m2f = rowLocal >> 4, tqf = (rowLocal >> 2) & 3, rf = rowLocal & 3;
    const int lf  = tqf * 16 + colF;
    float hold = 0.f;
    f32x4 accX = {0.f, 0.f, 0.f, 0.f};        // layer-0 x-part prefetch

    for (int i = 0; i <= TSTEPS; ++i) {
        const int t = layer ? (i - 1) : i;
        const bool valid = layer ? (t >= 0) : (t < TSTEPS);
        if (valid) {
            f32x4 accA = {0.f, 0.f, 0.f, 0.f};
            f32x4 accB = {0.f, 0.f, 0.f, 0.f};
            if (layer == 0) {
                if (i == 0) {
                    f32x4 xa = *(const f32x4*)(x + (size_t)t * (BATCH * IDIM) + arow * IDIM + kh * 32 + tq * 8);
                    f32x4 xb = *(const f32x4*)(x + (size_t)t * (BATCH * IDIM) + arow * IDIM + kh * 32 + tq * 8 + 4);
                    ks_r2(xa, xb, wfh[0], wfl[0], accA);
                } else {
                    accA = accX;   // prefetched under the previous barrier
                }
                if (t >= 1) {   // h0[t-1] = e0[t-1] = out[t-1][.][0][.]
                    const float* h0 = out + (size_t)(t - 1) * 131072 + arow * 2048
                                      + kh * 256 + tq * 8;
                    f32x4 bA[8], bB[8];
                    LDG4(bA, h0, 0);
                    LDG4(bB, h0, 1);
                    PROC4(bA, 1, 0);
                    PROC4(bB, 1, 1);
                }
            } else {
                // kh<2: e0[t] x Wi1 slice; kh>=2: h1[t-1] x Wh1 slice
                const bool doit = (kh < 2) || (t >= 1);
                if (doit) {
                    const int ts  = (kh < 2) ? t : (t - 1);
                    const float* src = out + (size_t)ts * 131072 + arow * 2048
                                       + ((kh < 2) ? 0 : 1024) + (kh & 1) * 512 + tq * 8;
                    f32x4 bA[8], bB[8];
                    LDG4(bA, src, 0);
                    LDG4(bB, src, 1);
                    PROC4(bA, 0, 0);
                    LDG4(bA, src, 2);
                    PROC4(bB, 0, 1);
                    LDG4(bB, src, 3);
                    PROC4(bA, 0, 2);
                    PROC4(bB, 0, 3);
                }
            }

            // cross-wave K-reduction (4 kh partials per m2)
            red[w * 64 + l] = accA + accB;
            __syncthreads();
            {   // all 512 threads finalize one output each
                float s = 0.f;
                #pragma unroll
                for (int k4 = 0; k4 < 4; ++k4)
                    s += red[(k4 * 2 + m2f) * 64 + lf][rf];
                const float hnew = 0.5f * hold + 0.5f * tanhf(s);
                hold = hnew;
                const int row = mh * 32 + rowLocal;
                float* dst = out + (size_t)t * 131072 + row * 2048 + layer * 1024 + jbase + colF;
                __hip_atomic_store(dst, hnew, __ATOMIC_RELAXED, __HIP_MEMORY_SCOPE_AGENT);
            }
            __syncthreads();   // red reuse safety
        }
        if (i < TSTEPS) {
            barrier_arrive(cnt, (unsigned)(i + 1));
            // overlap: layer-0's x-part for step i+1 is barrier-independent
            if (layer == 0 && (i + 1) < TSTEPS) {
                const float* xs = x + (size_t)(i + 1) * (BATCH * IDIM) + arow * IDIM + kh * 32 + tq * 8;
                f32x4 xa = *(const f32x4*)(xs);
                f32x4 xb = *(const f32x4*)(xs + 4);
                f32x4 z = {0.f, 0.f, 0.f, 0.f};
                ks_r2(xa, xb, wfh[0], wfl[0], z);
                accX = z;
            }
            barrier_wait(cnt, (unsigned)(i + 1), layer);
        }
    }
}

extern "C" void kernel_launch(void* const* d_in, const int* in_sizes, int n_in,
                              void* d_out, int out_size, void* d_ws, size_t ws_size,
                              hipStream_t stream) {
    const float* x   = (const float*)d_in[0];
    const float* Wi0 = (const float*)d_in[1];
    const float* Wh0 = (const float*)d_in[2];
    const float* Wi1 = (const float*)d_in[3];
    const float* Wh1 = (const float*)d_in[4];
    float* out = (float*)d_out;
    unsigned short* wsU = (unsigned short*)d_ws;
    unsigned* cnt = (unsigned*)((char*)d_ws + CNT_OFF_BYTES);

    // arrival + both flag arrays must be 0 at kernel start on EVERY replay
    hipMemsetAsync((char*)d_ws + CNT_OFF_BYTES, 0, BAR_BYTES, stream);
    prep_kernel<<<256, 256, 0, stream>>>(Wi0, Wh0, Wi1, Wh1, wsU);

    void* args[] = {(void*)&x, (void*)&out, (void*)&wsU, (void*)&cnt};
    hipLaunchCooperativeKernel((const void*)reservoir_kernel,
                               dim3(NBLOCKS), dim3(NTHR), args, 0, stream);
}